// Round 4
// baseline (663.496 us; speedup 1.0000x reference)
//
#include <hip/hip_runtime.h>

#define N_NODES 50000
#define N_EDGES 600000
#define F_IN    500
#define H_DIM   64
#define C_OUT   40
#define STEPS   4
#define NB_SCAN ((N_NODES + 255) / 256)   // 196

// ---------------- Encoder: h = x @ m1_w + m1_b ; z = x0 = h ----------------
// BM=64 rows/block (grid 782 -> ~3 blocks/CU), thread = 4 rows x 4 cols.
// x read direct from global (float4, 16-lane broadcast, L1-served);
// W staged in LDS in 64-row tiles (17.4 KB).
#define EBM 64
#define EBK 64
#define EWS_STRIDE (H_DIM + 4)   // 68

__global__ __launch_bounds__(256) void encoder_kernel(
    const float* __restrict__ x, const float* __restrict__ W,
    const float* __restrict__ b, float* __restrict__ x0, float* __restrict__ z)
{
    __shared__ __align__(16) float ws[EBK][EWS_STRIDE];

    int t  = threadIdx.x;
    int r0 = blockIdx.x * EBM;
    int tg = t >> 4;    // 0..15 row group -> rows tg*4..tg*4+3
    int tc = t & 15;    // col group -> cols tc*4..tc*4+3

    const float* xp[4];
    #pragma unroll
    for (int r = 0; r < 4; ++r) {
        int gr = r0 + tg * 4 + r;
        if (gr >= N_NODES) gr = N_NODES - 1;   // clamp loads, guard stores
        xp[r] = x + (size_t)gr * F_IN;
    }

    float acc[4][4];
    #pragma unroll
    for (int i = 0; i < 4; ++i)
        #pragma unroll
        for (int j = 0; j < 4; ++j) acc[i][j] = 0.f;

    for (int k0 = 0; k0 < 512; k0 += EBK) {
        // stage W tile: 64 k-rows x 64 cols = 1024 float4, 4 per thread
        #pragma unroll
        for (int s = 0; s < 4; ++s) {
            int idx  = s * 256 + t;
            int krow = idx >> 4;    // 0..63
            int f4c  = idx & 15;
            int gk   = k0 + krow;
            float4 v = make_float4(0.f, 0.f, 0.f, 0.f);
            if (gk < F_IN)
                v = *reinterpret_cast<const float4*>(W + (size_t)gk * H_DIM + f4c * 4);
            *reinterpret_cast<float4*>(&ws[krow][f4c * 4]) = v;
        }
        __syncthreads();

        int kqn = (F_IN - k0 < EBK ? F_IN - k0 : EBK) >> 2;   // 16 or 13
        for (int kq = 0; kq < kqn; ++kq) {
            int kb = k0 + kq * 4;
            float4 xv[4];
            #pragma unroll
            for (int r = 0; r < 4; ++r)
                xv[r] = *reinterpret_cast<const float4*>(xp[r] + kb);
            float4 wv[4];
            #pragma unroll
            for (int j = 0; j < 4; ++j)
                wv[j] = *reinterpret_cast<const float4*>(&ws[kq * 4 + j][tc * 4]);

            float xr[4][4] = {
                {xv[0].x, xv[0].y, xv[0].z, xv[0].w},
                {xv[1].x, xv[1].y, xv[1].z, xv[1].w},
                {xv[2].x, xv[2].y, xv[2].z, xv[2].w},
                {xv[3].x, xv[3].y, xv[3].z, xv[3].w}};
            float wr[4][4] = {
                {wv[0].x, wv[0].y, wv[0].z, wv[0].w},
                {wv[1].x, wv[1].y, wv[1].z, wv[1].w},
                {wv[2].x, wv[2].y, wv[2].z, wv[2].w},
                {wv[3].x, wv[3].y, wv[3].z, wv[3].w}};
            #pragma unroll
            for (int j = 0; j < 4; ++j)
                #pragma unroll
                for (int r = 0; r < 4; ++r)
                    #pragma unroll
                    for (int c = 0; c < 4; ++c)
                        acc[r][c] = fmaf(xr[r][j], wr[j][c], acc[r][c]);
        }
        __syncthreads();
    }

    float4 bias = *reinterpret_cast<const float4*>(b + tc * 4);
    #pragma unroll
    for (int r = 0; r < 4; ++r) {
        int gr = r0 + tg * 4 + r;
        if (gr < N_NODES) {
            float4 v;
            v.x = acc[r][0] + bias.x;
            v.y = acc[r][1] + bias.y;
            v.z = acc[r][2] + bias.z;
            v.w = acc[r][3] + bias.w;
            size_t idx = (size_t)gr * H_DIM + tc * 4;
            *reinterpret_cast<float4*>(x0 + idx) = v;
            *reinterpret_cast<float4*>(z  + idx) = v;
        }
    }
}

// ---------------- CSR build ----------------
__global__ void hist_kernel(const int* __restrict__ src, int* __restrict__ counts)
{
    int e = blockIdx.x * 256 + threadIdx.x;
    if (e < N_EDGES) atomicAdd(&counts[src[e]], 1);
}

__global__ __launch_bounds__(256) void scanA_kernel(
    const int* __restrict__ counts, int* __restrict__ blockSums)
{
    __shared__ int red[256];
    int i = blockIdx.x * 256 + threadIdx.x;
    red[threadIdx.x] = (i < N_NODES) ? counts[i] : 0;
    __syncthreads();
    #pragma unroll
    for (int s = 128; s > 0; s >>= 1) {
        if (threadIdx.x < s) red[threadIdx.x] += red[threadIdx.x + s];
        __syncthreads();
    }
    if (threadIdx.x == 0) blockSums[blockIdx.x] = red[0];
}

__global__ __launch_bounds__(256) void scanB_kernel(
    const int* __restrict__ blockSums, int* __restrict__ blockBases)
{
    __shared__ int s[256];
    int tid = threadIdx.x;
    int v = (tid < NB_SCAN) ? blockSums[tid] : 0;
    s[tid] = v;
    __syncthreads();
    #pragma unroll
    for (int d = 1; d < 256; d <<= 1) {
        int t = (tid >= d) ? s[tid - d] : 0;
        __syncthreads();
        s[tid] += t;
        __syncthreads();
    }
    if (tid < NB_SCAN) blockBases[tid] = s[tid] - v;
}

__global__ __launch_bounds__(256) void scanC_kernel(
    const int* __restrict__ counts, const int* __restrict__ blockBases,
    int* __restrict__ off, int* __restrict__ cursor)
{
    __shared__ int s[256];
    int tid = threadIdx.x;
    int i = blockIdx.x * 256 + tid;
    int v = (i < N_NODES) ? counts[i] : 0;
    s[tid] = v;
    __syncthreads();
    #pragma unroll
    for (int d = 1; d < 256; d <<= 1) {
        int t = (tid >= d) ? s[tid - d] : 0;
        __syncthreads();
        s[tid] += t;
        __syncthreads();
    }
    if (i < N_NODES) {
        int excl = blockBases[blockIdx.x] + s[tid] - v;
        off[i] = excl;
        cursor[i] = excl;
        if (i == N_NODES - 1) off[N_NODES] = excl + v;
    }
}

__global__ void scatter_kernel(const int* __restrict__ src, const int* __restrict__ dst,
                               const float* __restrict__ w,
                               int* __restrict__ cursor, int2* __restrict__ epack)
{
    int e = blockIdx.x * 256 + threadIdx.x;
    if (e < N_EDGES) {
        int s = src[e];
        int p = atomicAdd(&cursor[s], 1);
        epack[p] = make_int2(dst[e], __float_as_int(w[e]));
    }
}

// ---------------- Fused RK4 stage ----------------
__global__ __launch_bounds__(256) void stage_kernel(
    const int* __restrict__ off, const int2* __restrict__ epack,
    const float* __restrict__ zs, const float* zbase,
    const float* __restrict__ x0, const float* __restrict__ alpha,
    float* __restrict__ acc, float* out,
    int stage, float cnext)
{
    int node = blockIdx.x * 16 + (threadIdx.x >> 4);
    if (node >= N_NODES) return;
    int c = (threadIdx.x & 15) << 2;

    int jb = off[node], je = off[node + 1];
    float4 az0 = make_float4(0.f, 0.f, 0.f, 0.f);
    float4 az1 = make_float4(0.f, 0.f, 0.f, 0.f);
    float4 az2 = make_float4(0.f, 0.f, 0.f, 0.f);
    float4 az3 = make_float4(0.f, 0.f, 0.f, 0.f);
    int j = jb;
    for (; j + 3 < je; j += 4) {
        int2 e0 = epack[j];
        int2 e1 = epack[j + 1];
        int2 e2 = epack[j + 2];
        int2 e3 = epack[j + 3];
        const float4 z0 = *reinterpret_cast<const float4*>(zs + (size_t)e0.x * H_DIM + c);
        const float4 z1 = *reinterpret_cast<const float4*>(zs + (size_t)e1.x * H_DIM + c);
        const float4 z2 = *reinterpret_cast<const float4*>(zs + (size_t)e2.x * H_DIM + c);
        const float4 z3 = *reinterpret_cast<const float4*>(zs + (size_t)e3.x * H_DIM + c);
        float w0 = __int_as_float(e0.y), w1 = __int_as_float(e1.y);
        float w2 = __int_as_float(e2.y), w3 = __int_as_float(e3.y);
        az0.x = fmaf(w0, z0.x, az0.x); az0.y = fmaf(w0, z0.y, az0.y);
        az0.z = fmaf(w0, z0.z, az0.z); az0.w = fmaf(w0, z0.w, az0.w);
        az1.x = fmaf(w1, z1.x, az1.x); az1.y = fmaf(w1, z1.y, az1.y);
        az1.z = fmaf(w1, z1.z, az1.z); az1.w = fmaf(w1, z1.w, az1.w);
        az2.x = fmaf(w2, z2.x, az2.x); az2.y = fmaf(w2, z2.y, az2.y);
        az2.z = fmaf(w2, z2.z, az2.z); az2.w = fmaf(w2, z2.w, az2.w);
        az3.x = fmaf(w3, z3.x, az3.x); az3.y = fmaf(w3, z3.y, az3.y);
        az3.z = fmaf(w3, z3.z, az3.z); az3.w = fmaf(w3, z3.w, az3.w);
    }
    for (; j < je; ++j) {
        int2 e0 = epack[j];
        const float4 z0 = *reinterpret_cast<const float4*>(zs + (size_t)e0.x * H_DIM + c);
        float w0 = __int_as_float(e0.y);
        az0.x = fmaf(w0, z0.x, az0.x); az0.y = fmaf(w0, z0.y, az0.y);
        az0.z = fmaf(w0, z0.z, az0.z); az0.w = fmaf(w0, z0.w, az0.w);
    }
    float4 az;
    az.x = (az0.x + az1.x) + (az2.x + az3.x);
    az.y = (az0.y + az1.y) + (az2.y + az3.y);
    az.z = (az0.z + az1.z) + (az2.z + az3.z);
    az.w = (az0.w + az1.w) + (az2.w + az3.w);

    size_t idx = (size_t)node * H_DIM + c;
    const float4 zsv = *reinterpret_cast<const float4*>(zs + idx);
    const float4 x0v = *reinterpret_cast<const float4*>(x0 + idx);
    float a = 0.5f / (1.f + __expf(-alpha[node]));

    float4 k;
    k.x = fmaf(a, az.x - zsv.x, x0v.x);
    k.y = fmaf(a, az.y - zsv.y, x0v.y);
    k.z = fmaf(a, az.z - zsv.z, x0v.z);
    k.w = fmaf(a, az.w - zsv.w, x0v.w);

    float4 zb = *reinterpret_cast<const float4*>(zbase + idx);
    float4 o;
    if (stage == 3) {
        float4 av = *reinterpret_cast<const float4*>(acc + idx);
        o.x = fmaf(cnext, av.x + k.x, zb.x);
        o.y = fmaf(cnext, av.y + k.y, zb.y);
        o.z = fmaf(cnext, av.z + k.z, zb.z);
        o.w = fmaf(cnext, av.w + k.w, zb.w);
    } else {
        if (stage == 0) {
            *reinterpret_cast<float4*>(acc + idx) = k;
        } else {
            float4 av = *reinterpret_cast<const float4*>(acc + idx);
            av.x = fmaf(2.f, k.x, av.x);
            av.y = fmaf(2.f, k.y, av.y);
            av.z = fmaf(2.f, k.z, av.z);
            av.w = fmaf(2.f, k.w, av.w);
            *reinterpret_cast<float4*>(acc + idx) = av;
        }
        o.x = fmaf(cnext, k.x, zb.x);
        o.y = fmaf(cnext, k.y, zb.y);
        o.z = fmaf(cnext, k.z, zb.z);
        o.w = fmaf(cnext, k.w, zb.w);
    }
    *reinterpret_cast<float4*>(out + idx) = o;
}

// ---------------- Decoder: out = relu(z) @ m2_w + m2_b ----------------
// One wave per node: coalesced z load -> LDS, then 40 lanes do the dot.
__global__ __launch_bounds__(256) void decoder_kernel(
    const float* __restrict__ z, const float* __restrict__ W2,
    const float* __restrict__ b2, float* __restrict__ out)
{
    __shared__ float zsm[4][H_DIM];
    int lane = threadIdx.x & 63;
    int w    = threadIdx.x >> 6;
    int node = blockIdx.x * 4 + w;
    int ld   = node >= N_NODES ? N_NODES - 1 : node;
    float zv = z[(size_t)ld * H_DIM + lane];
    zsm[w][lane] = zv > 0.f ? zv : 0.f;
    __syncthreads();
    if (node < N_NODES && lane < C_OUT) {
        float acc = b2[lane];
        #pragma unroll
        for (int k = 0; k < H_DIM; ++k)
            acc = fmaf(zsm[w][k], W2[k * C_OUT + lane], acc);
        out[(size_t)node * C_OUT + lane] = acc;
    }
}

extern "C" void kernel_launch(void* const* d_in, const int* in_sizes, int n_in,
                              void* d_out, int out_size, void* d_ws, size_t ws_size,
                              hipStream_t stream)
{
    const float* x     = (const float*)d_in[0];
    const float* ew    = (const float*)d_in[1];
    const float* m1w   = (const float*)d_in[2];
    const float* m1b   = (const float*)d_in[3];
    const float* alpha = (const float*)d_in[4];
    const float* m2w   = (const float*)d_in[5];
    const float* m2b   = (const float*)d_in[6];
    const int*   esrc  = (const int*)d_in[7];
    const int*   edst  = (const int*)d_in[8];
    float* out = (float*)d_out;

    char* ws = (char*)d_ws;
    size_t o = 0;
    auto alloc = [&](size_t bytes) -> void* {
        void* p = ws + o;
        o = (o + bytes + 255) & ~(size_t)255;
        return p;
    };
    float* x0      = (float*)alloc((size_t)N_NODES * H_DIM * 4);
    float* z       = (float*)alloc((size_t)N_NODES * H_DIM * 4);
    float* ztA     = (float*)alloc((size_t)N_NODES * H_DIM * 4);
    float* ztB     = (float*)alloc((size_t)N_NODES * H_DIM * 4);
    float* acc     = (float*)alloc((size_t)N_NODES * H_DIM * 4);
    int*   counts  = (int*)alloc((size_t)N_NODES * 4);
    int*   off     = (int*)alloc((size_t)(N_NODES + 1) * 4);
    int*   cursor  = (int*)alloc((size_t)N_NODES * 4);
    int*   bsums   = (int*)alloc((size_t)NB_SCAN * 4);
    int*   bbases  = (int*)alloc((size_t)NB_SCAN * 4);
    int2*  epack   = (int2*)alloc((size_t)N_EDGES * 8);

    hipMemsetAsync(counts, 0, (size_t)N_NODES * 4, stream);
    hist_kernel<<<(N_EDGES + 255) / 256, 256, 0, stream>>>(esrc, counts);
    scanA_kernel<<<NB_SCAN, 256, 0, stream>>>(counts, bsums);
    scanB_kernel<<<1, 256, 0, stream>>>(bsums, bbases);
    scanC_kernel<<<NB_SCAN, 256, 0, stream>>>(counts, bbases, off, cursor);
    scatter_kernel<<<(N_EDGES + 255) / 256, 256, 0, stream>>>(esrc, edst, ew, cursor, epack);

    encoder_kernel<<<(N_NODES + EBM - 1) / EBM, 256, 0, stream>>>(x, m1w, m1b, x0, z);

    const float dt = 1.0f / STEPS;
    int sgrid = (N_NODES + 15) / 16;
    for (int step = 0; step < STEPS; ++step) {
        stage_kernel<<<sgrid, 256, 0, stream>>>(off, epack, z,   z, x0, alpha, acc, ztA, 0, 0.5f * dt);
        stage_kernel<<<sgrid, 256, 0, stream>>>(off, epack, ztA, z, x0, alpha, acc, ztB, 1, 0.5f * dt);
        stage_kernel<<<sgrid, 256, 0, stream>>>(off, epack, ztB, z, x0, alpha, acc, ztA, 2, dt);
        stage_kernel<<<sgrid, 256, 0, stream>>>(off, epack, ztA, z, x0, alpha, acc, z,   3, dt / 6.0f);
    }

    decoder_kernel<<<(N_NODES + 3) / 4, 256, 0, stream>>>(z, m2w, m2b, out);
}

// Round 5
// 574.496 us; speedup vs baseline: 1.1549x; 1.1549x over previous
//
#include <hip/hip_runtime.h>
#include <hip/hip_fp16.h>

#define N_NODES 50000
#define N_EDGES 600000
#define F_IN    500
#define H_DIM   64
#define C_OUT   40
#define STEPS   4
#define NB_SCAN ((N_NODES + 255) / 256)   // 196

// ---------------- Encoder: h = x @ m1_w + m1_b ; z = x0 = h (+ fp16 copy) --
// BM=32 rows/block, thread = 4 rows x 2 cols (8 outputs) -> 6250 waves total
// (~24 waves/CU). W staged in LDS; x direct-global broadcast loads.
#define EBM 32
#define EBK 64
#define EWS_STRIDE (H_DIM + 4)   // 68

#define ENC_BODY(KQ)                                                           \
    {                                                                          \
        const int kb = k0 + (KQ) * 4;                                          \
        float4 xv0 = *reinterpret_cast<const float4*>(xp[0] + kb);             \
        float4 xv1 = *reinterpret_cast<const float4*>(xp[1] + kb);             \
        float4 xv2 = *reinterpret_cast<const float4*>(xp[2] + kb);             \
        float4 xv3 = *reinterpret_cast<const float4*>(xp[3] + kb);             \
        float2 wv0 = *reinterpret_cast<const float2*>(&ws[(KQ) * 4 + 0][tc * 2]); \
        float2 wv1 = *reinterpret_cast<const float2*>(&ws[(KQ) * 4 + 1][tc * 2]); \
        float2 wv2 = *reinterpret_cast<const float2*>(&ws[(KQ) * 4 + 2][tc * 2]); \
        float2 wv3 = *reinterpret_cast<const float2*>(&ws[(KQ) * 4 + 3][tc * 2]); \
        acc[0][0] = fmaf(xv0.x, wv0.x, acc[0][0]); acc[0][1] = fmaf(xv0.x, wv0.y, acc[0][1]); \
        acc[1][0] = fmaf(xv1.x, wv0.x, acc[1][0]); acc[1][1] = fmaf(xv1.x, wv0.y, acc[1][1]); \
        acc[2][0] = fmaf(xv2.x, wv0.x, acc[2][0]); acc[2][1] = fmaf(xv2.x, wv0.y, acc[2][1]); \
        acc[3][0] = fmaf(xv3.x, wv0.x, acc[3][0]); acc[3][1] = fmaf(xv3.x, wv0.y, acc[3][1]); \
        acc[0][0] = fmaf(xv0.y, wv1.x, acc[0][0]); acc[0][1] = fmaf(xv0.y, wv1.y, acc[0][1]); \
        acc[1][0] = fmaf(xv1.y, wv1.x, acc[1][0]); acc[1][1] = fmaf(xv1.y, wv1.y, acc[1][1]); \
        acc[2][0] = fmaf(xv2.y, wv1.x, acc[2][0]); acc[2][1] = fmaf(xv2.y, wv1.y, acc[2][1]); \
        acc[3][0] = fmaf(xv3.y, wv1.x, acc[3][0]); acc[3][1] = fmaf(xv3.y, wv1.y, acc[3][1]); \
        acc[0][0] = fmaf(xv0.z, wv2.x, acc[0][0]); acc[0][1] = fmaf(xv0.z, wv2.y, acc[0][1]); \
        acc[1][0] = fmaf(xv1.z, wv2.x, acc[1][0]); acc[1][1] = fmaf(xv1.z, wv2.y, acc[1][1]); \
        acc[2][0] = fmaf(xv2.z, wv2.x, acc[2][0]); acc[2][1] = fmaf(xv2.z, wv2.y, acc[2][1]); \
        acc[3][0] = fmaf(xv3.z, wv2.x, acc[3][0]); acc[3][1] = fmaf(xv3.z, wv2.y, acc[3][1]); \
        acc[0][0] = fmaf(xv0.w, wv3.x, acc[0][0]); acc[0][1] = fmaf(xv0.w, wv3.y, acc[0][1]); \
        acc[1][0] = fmaf(xv1.w, wv3.x, acc[1][0]); acc[1][1] = fmaf(xv1.w, wv3.y, acc[1][1]); \
        acc[2][0] = fmaf(xv2.w, wv3.x, acc[2][0]); acc[2][1] = fmaf(xv2.w, wv3.y, acc[2][1]); \
        acc[3][0] = fmaf(xv3.w, wv3.x, acc[3][0]); acc[3][1] = fmaf(xv3.w, wv3.y, acc[3][1]); \
    }

__global__ __launch_bounds__(256) void encoder_kernel(
    const float* __restrict__ x, const float* __restrict__ W,
    const float* __restrict__ b, float* __restrict__ x0, float* __restrict__ z,
    __half* __restrict__ zH)
{
    __shared__ __align__(16) float ws[EBK][EWS_STRIDE];

    int t  = threadIdx.x;
    int r0 = blockIdx.x * EBM;
    int tg = t >> 5;    // 0..7 -> rows tg*4..tg*4+3
    int tc = t & 31;    // cols tc*2, tc*2+1

    const float* xp[4];
    #pragma unroll
    for (int r = 0; r < 4; ++r) {
        int gr = r0 + tg * 4 + r;
        if (gr >= N_NODES) gr = N_NODES - 1;
        xp[r] = x + (size_t)gr * F_IN;
    }

    float acc[4][2];
    #pragma unroll
    for (int i = 0; i < 4; ++i) { acc[i][0] = 0.f; acc[i][1] = 0.f; }

    for (int k0 = 0; k0 < 512; k0 += EBK) {
        // stage W tile: 64 k-rows x 64 cols = 1024 float4, 4 per thread
        #pragma unroll
        for (int s = 0; s < 4; ++s) {
            int idx  = s * 256 + t;
            int krow = idx >> 4;
            int f4c  = idx & 15;
            int gk   = k0 + krow;
            float4 v = make_float4(0.f, 0.f, 0.f, 0.f);
            if (gk < F_IN)
                v = *reinterpret_cast<const float4*>(W + (size_t)gk * H_DIM + f4c * 4);
            *reinterpret_cast<float4*>(&ws[krow][f4c * 4]) = v;
        }
        __syncthreads();

        if (k0 + EBK <= F_IN) {
            #pragma unroll
            for (int kq = 0; kq < 16; ++kq) ENC_BODY(kq)
        } else {
            #pragma unroll
            for (int kq = 0; kq < 13; ++kq) ENC_BODY(kq)
        }
        __syncthreads();
    }

    float2 bias = *reinterpret_cast<const float2*>(b + tc * 2);
    #pragma unroll
    for (int r = 0; r < 4; ++r) {
        int gr = r0 + tg * 4 + r;
        if (gr < N_NODES) {
            float2 v;
            v.x = acc[r][0] + bias.x;
            v.y = acc[r][1] + bias.y;
            size_t idx = (size_t)gr * H_DIM + tc * 2;
            *reinterpret_cast<float2*>(x0 + idx) = v;
            *reinterpret_cast<float2*>(z  + idx) = v;
            *reinterpret_cast<__half2*>(zH + idx) = __float22half2_rn(v);
        }
    }
}

// ---------------- CSR build ----------------
__global__ void hist_kernel(const int* __restrict__ src, int* __restrict__ counts)
{
    int e = blockIdx.x * 256 + threadIdx.x;
    if (e < N_EDGES) atomicAdd(&counts[src[e]], 1);
}

__global__ __launch_bounds__(256) void scanA_kernel(
    const int* __restrict__ counts, int* __restrict__ blockSums)
{
    __shared__ int red[256];
    int i = blockIdx.x * 256 + threadIdx.x;
    red[threadIdx.x] = (i < N_NODES) ? counts[i] : 0;
    __syncthreads();
    #pragma unroll
    for (int s = 128; s > 0; s >>= 1) {
        if (threadIdx.x < s) red[threadIdx.x] += red[threadIdx.x + s];
        __syncthreads();
    }
    if (threadIdx.x == 0) blockSums[blockIdx.x] = red[0];
}

__global__ __launch_bounds__(256) void scanB_kernel(
    const int* __restrict__ blockSums, int* __restrict__ blockBases)
{
    __shared__ int s[256];
    int tid = threadIdx.x;
    int v = (tid < NB_SCAN) ? blockSums[tid] : 0;
    s[tid] = v;
    __syncthreads();
    #pragma unroll
    for (int d = 1; d < 256; d <<= 1) {
        int t = (tid >= d) ? s[tid - d] : 0;
        __syncthreads();
        s[tid] += t;
        __syncthreads();
    }
    if (tid < NB_SCAN) blockBases[tid] = s[tid] - v;
}

__global__ __launch_bounds__(256) void scanC_kernel(
    const int* __restrict__ counts, const int* __restrict__ blockBases,
    int* __restrict__ off, int* __restrict__ cursor)
{
    __shared__ int s[256];
    int tid = threadIdx.x;
    int i = blockIdx.x * 256 + tid;
    int v = (i < N_NODES) ? counts[i] : 0;
    s[tid] = v;
    __syncthreads();
    #pragma unroll
    for (int d = 1; d < 256; d <<= 1) {
        int t = (tid >= d) ? s[tid - d] : 0;
        __syncthreads();
        s[tid] += t;
        __syncthreads();
    }
    if (i < N_NODES) {
        int excl = blockBases[blockIdx.x] + s[tid] - v;
        off[i] = excl;
        cursor[i] = excl;
        if (i == N_NODES - 1) off[N_NODES] = excl + v;
    }
}

__global__ void scatter_kernel(const int* __restrict__ src, const int* __restrict__ dst,
                               const float* __restrict__ w,
                               int* __restrict__ cursor, int2* __restrict__ epack)
{
    int e = blockIdx.x * 256 + threadIdx.x;
    if (e < N_EDGES) {
        int s = src[e];
        int p = atomicAdd(&cursor[s], 1);
        epack[p] = make_int2(dst[e], __float_as_int(w[e]));
    }
}

// ---------------- Fused RK4 stage (fp16 gather + self, fp32 streams) -------
// zsH: fp16 stage input (gather + self). zb: fp32 z (RK base). outH: fp16
// stage output. Stage 3 additionally writes fp32 z to outZ.
__global__ __launch_bounds__(256) void stage_kernel(
    const int* __restrict__ off, const int2* __restrict__ epack,
    const __half* __restrict__ zsH, const float* __restrict__ zb,
    const float* __restrict__ x0, const float* __restrict__ alpha,
    float* __restrict__ acc, __half* __restrict__ outH,
    float* __restrict__ outZ, int stage, float cnext)
{
    int node = blockIdx.x * 16 + (threadIdx.x >> 4);
    if (node >= N_NODES) return;
    int c = (threadIdx.x & 15) << 2;

    int jb = off[node], je = off[node + 1];
    float4 az0 = make_float4(0.f, 0.f, 0.f, 0.f);
    float4 az1 = make_float4(0.f, 0.f, 0.f, 0.f);
    float4 az2 = make_float4(0.f, 0.f, 0.f, 0.f);
    float4 az3 = make_float4(0.f, 0.f, 0.f, 0.f);

    union HC { uint2 u; __half2 h[2]; };

    int j = jb;
    for (; j + 3 < je; j += 4) {
        int2 e0 = epack[j];
        int2 e1 = epack[j + 1];
        int2 e2 = epack[j + 2];
        int2 e3 = epack[j + 3];
        HC r0, r1, r2, r3;
        r0.u = *reinterpret_cast<const uint2*>(zsH + (size_t)e0.x * H_DIM + c);
        r1.u = *reinterpret_cast<const uint2*>(zsH + (size_t)e1.x * H_DIM + c);
        r2.u = *reinterpret_cast<const uint2*>(zsH + (size_t)e2.x * H_DIM + c);
        r3.u = *reinterpret_cast<const uint2*>(zsH + (size_t)e3.x * H_DIM + c);
        float w0 = __int_as_float(e0.y), w1 = __int_as_float(e1.y);
        float w2 = __int_as_float(e2.y), w3 = __int_as_float(e3.y);
        float2 lo, hi;
        lo = __half22float2(r0.h[0]); hi = __half22float2(r0.h[1]);
        az0.x = fmaf(w0, lo.x, az0.x); az0.y = fmaf(w0, lo.y, az0.y);
        az0.z = fmaf(w0, hi.x, az0.z); az0.w = fmaf(w0, hi.y, az0.w);
        lo = __half22float2(r1.h[0]); hi = __half22float2(r1.h[1]);
        az1.x = fmaf(w1, lo.x, az1.x); az1.y = fmaf(w1, lo.y, az1.y);
        az1.z = fmaf(w1, hi.x, az1.z); az1.w = fmaf(w1, hi.y, az1.w);
        lo = __half22float2(r2.h[0]); hi = __half22float2(r2.h[1]);
        az2.x = fmaf(w2, lo.x, az2.x); az2.y = fmaf(w2, lo.y, az2.y);
        az2.z = fmaf(w2, hi.x, az2.z); az2.w = fmaf(w2, hi.y, az2.w);
        lo = __half22float2(r3.h[0]); hi = __half22float2(r3.h[1]);
        az3.x = fmaf(w3, lo.x, az3.x); az3.y = fmaf(w3, lo.y, az3.y);
        az3.z = fmaf(w3, hi.x, az3.z); az3.w = fmaf(w3, hi.y, az3.w);
    }
    for (; j < je; ++j) {
        int2 e0 = epack[j];
        HC r0;
        r0.u = *reinterpret_cast<const uint2*>(zsH + (size_t)e0.x * H_DIM + c);
        float w0 = __int_as_float(e0.y);
        float2 lo = __half22float2(r0.h[0]);
        float2 hi = __half22float2(r0.h[1]);
        az0.x = fmaf(w0, lo.x, az0.x); az0.y = fmaf(w0, lo.y, az0.y);
        az0.z = fmaf(w0, hi.x, az0.z); az0.w = fmaf(w0, hi.y, az0.w);
    }
    float4 az;
    az.x = (az0.x + az1.x) + (az2.x + az3.x);
    az.y = (az0.y + az1.y) + (az2.y + az3.y);
    az.z = (az0.z + az1.z) + (az2.z + az3.z);
    az.w = (az0.w + az1.w) + (az2.w + az3.w);

    size_t idx = (size_t)node * H_DIM + c;
    HC sr; sr.u = *reinterpret_cast<const uint2*>(zsH + idx);
    float2 slo = __half22float2(sr.h[0]);
    float2 shi = __half22float2(sr.h[1]);
    const float4 x0v = *reinterpret_cast<const float4*>(x0 + idx);
    float a = 0.5f / (1.f + __expf(-alpha[node]));

    float4 k;
    k.x = fmaf(a, az.x - slo.x, x0v.x);
    k.y = fmaf(a, az.y - slo.y, x0v.y);
    k.z = fmaf(a, az.z - shi.x, x0v.z);
    k.w = fmaf(a, az.w - shi.y, x0v.w);

    float4 zbv = *reinterpret_cast<const float4*>(zb + idx);
    float4 o;
    if (stage == 3) {
        float4 av = *reinterpret_cast<const float4*>(acc + idx);
        o.x = fmaf(cnext, av.x + k.x, zbv.x);
        o.y = fmaf(cnext, av.y + k.y, zbv.y);
        o.z = fmaf(cnext, av.z + k.z, zbv.z);
        o.w = fmaf(cnext, av.w + k.w, zbv.w);
        *reinterpret_cast<float4*>(outZ + idx) = o;
    } else {
        if (stage == 0) {
            *reinterpret_cast<float4*>(acc + idx) = k;
        } else {
            float4 av = *reinterpret_cast<const float4*>(acc + idx);
            av.x = fmaf(2.f, k.x, av.x);
            av.y = fmaf(2.f, k.y, av.y);
            av.z = fmaf(2.f, k.z, av.z);
            av.w = fmaf(2.f, k.w, av.w);
            *reinterpret_cast<float4*>(acc + idx) = av;
        }
        o.x = fmaf(cnext, k.x, zbv.x);
        o.y = fmaf(cnext, k.y, zbv.y);
        o.z = fmaf(cnext, k.z, zbv.z);
        o.w = fmaf(cnext, k.w, zbv.w);
    }
    HC sv;
    sv.h[0] = __float22half2_rn(make_float2(o.x, o.y));
    sv.h[1] = __float22half2_rn(make_float2(o.z, o.w));
    *reinterpret_cast<uint2*>(outH + idx) = sv.u;
}

// ---------------- Decoder: out = relu(z) @ m2_w + m2_b ----------------
__global__ __launch_bounds__(256) void decoder_kernel(
    const float* __restrict__ z, const float* __restrict__ W2,
    const float* __restrict__ b2, float* __restrict__ out)
{
    __shared__ float zsm[4][H_DIM];
    int lane = threadIdx.x & 63;
    int w    = threadIdx.x >> 6;
    int node = blockIdx.x * 4 + w;
    int ld   = node >= N_NODES ? N_NODES - 1 : node;
    float zv = z[(size_t)ld * H_DIM + lane];
    zsm[w][lane] = zv > 0.f ? zv : 0.f;
    __syncthreads();
    if (node < N_NODES && lane < C_OUT) {
        float acc = b2[lane];
        #pragma unroll
        for (int k = 0; k < H_DIM; ++k)
            acc = fmaf(zsm[w][k], W2[k * C_OUT + lane], acc);
        out[(size_t)node * C_OUT + lane] = acc;
    }
}

extern "C" void kernel_launch(void* const* d_in, const int* in_sizes, int n_in,
                              void* d_out, int out_size, void* d_ws, size_t ws_size,
                              hipStream_t stream)
{
    const float* x     = (const float*)d_in[0];
    const float* ew    = (const float*)d_in[1];
    const float* m1w   = (const float*)d_in[2];
    const float* m1b   = (const float*)d_in[3];
    const float* alpha = (const float*)d_in[4];
    const float* m2w   = (const float*)d_in[5];
    const float* m2b   = (const float*)d_in[6];
    const int*   esrc  = (const int*)d_in[7];
    const int*   edst  = (const int*)d_in[8];
    float* out = (float*)d_out;

    char* ws = (char*)d_ws;
    size_t o = 0;
    auto alloc = [&](size_t bytes) -> void* {
        void* p = ws + o;
        o = (o + bytes + 255) & ~(size_t)255;
        return p;
    };
    float*  x0     = (float*)alloc((size_t)N_NODES * H_DIM * 4);
    float*  z      = (float*)alloc((size_t)N_NODES * H_DIM * 4);
    float*  acc    = (float*)alloc((size_t)N_NODES * H_DIM * 4);
    __half* zH     = (__half*)alloc((size_t)N_NODES * H_DIM * 2);
    __half* ztAH   = (__half*)alloc((size_t)N_NODES * H_DIM * 2);
    __half* ztBH   = (__half*)alloc((size_t)N_NODES * H_DIM * 2);
    int*    counts = (int*)alloc((size_t)N_NODES * 4);
    int*    off    = (int*)alloc((size_t)(N_NODES + 1) * 4);
    int*    cursor = (int*)alloc((size_t)N_NODES * 4);
    int*    bsums  = (int*)alloc((size_t)NB_SCAN * 4);
    int*    bbases = (int*)alloc((size_t)NB_SCAN * 4);
    int2*   epack  = (int2*)alloc((size_t)N_EDGES * 8);

    hipMemsetAsync(counts, 0, (size_t)N_NODES * 4, stream);
    hist_kernel<<<(N_EDGES + 255) / 256, 256, 0, stream>>>(esrc, counts);
    scanA_kernel<<<NB_SCAN, 256, 0, stream>>>(counts, bsums);
    scanB_kernel<<<1, 256, 0, stream>>>(bsums, bbases);
    scanC_kernel<<<NB_SCAN, 256, 0, stream>>>(counts, bbases, off, cursor);
    scatter_kernel<<<(N_EDGES + 255) / 256, 256, 0, stream>>>(esrc, edst, ew, cursor, epack);

    encoder_kernel<<<(N_NODES + EBM - 1) / EBM, 256, 0, stream>>>(x, m1w, m1b, x0, z, zH);

    const float dt = 1.0f / STEPS;
    int sgrid = (N_NODES + 15) / 16;
    for (int step = 0; step < STEPS; ++step) {
        stage_kernel<<<sgrid, 256, 0, stream>>>(off, epack, zH,   z, x0, alpha, acc, ztAH, nullptr, 0, 0.5f * dt);
        stage_kernel<<<sgrid, 256, 0, stream>>>(off, epack, ztAH, z, x0, alpha, acc, ztBH, nullptr, 1, 0.5f * dt);
        stage_kernel<<<sgrid, 256, 0, stream>>>(off, epack, ztBH, z, x0, alpha, acc, ztAH, nullptr, 2, dt);
        stage_kernel<<<sgrid, 256, 0, stream>>>(off, epack, ztAH, z, x0, alpha, acc, zH,   z,       3, dt / 6.0f);
    }

    decoder_kernel<<<(N_NODES + 3) / 4, 256, 0, stream>>>(z, m2w, m2b, out);
}

// Round 6
// 489.387 us; speedup vs baseline: 1.3558x; 1.1739x over previous
//
#include <hip/hip_runtime.h>
#include <hip/hip_fp16.h>

#define N_NODES 50000
#define N_EDGES 600000
#define F_IN    500
#define H_DIM   64
#define C_OUT   40
#define STEPS   4
#define NB_SCAN ((N_NODES + 255) / 256)   // 196
#define KTILES  16                        // 512 k padded, 32 per MFMA

using half8 = __attribute__((ext_vector_type(8))) _Float16;
using f32x4 = __attribute__((ext_vector_type(4))) float;

// ---------------- B-fragment precompute: W (500x64 f32) -> MFMA frags ------
// frag index t = kt*256 + c*64 + lane ; element j: B[k][col],
// col = c*16 + (lane&15), k = kt*32 + (lane>>4)*8 + j (0 if k >= 500).
__global__ __launch_bounds__(256) void bfrag_kernel(
    const float* __restrict__ W, __half* __restrict__ bfrag)
{
    int t = blockIdx.x * 256 + threadIdx.x;
    if (t >= KTILES * 4 * 64) return;
    int lane = t & 63;
    int c    = (t >> 6) & 3;
    int kt   = t >> 8;
    int col  = c * 16 + (lane & 15);
    int kb   = kt * 32 + (lane >> 4) * 8;
    union { uint4 u; __half h[8]; } v;
    #pragma unroll
    for (int j = 0; j < 8; ++j) {
        int k = kb + j;
        v.h[j] = (k < F_IN) ? __float2half(W[(size_t)k * H_DIM + col]) : __half(0.f);
    }
    *reinterpret_cast<uint4*>(bfrag + (size_t)t * 8) = v.u;
}

// ---------------- Encoder: MFMA GEMM, 64 rows/block (4 waves x 16) --------
__global__ __launch_bounds__(256) void encoder_kernel(
    const float* __restrict__ x, const __half* __restrict__ bfrag,
    const float* __restrict__ b, float* __restrict__ x0, float* __restrict__ z,
    __half* __restrict__ zH)
{
    int wave = threadIdx.x >> 6;
    int lane = threadIdx.x & 63;
    int rowl = lane & 15;
    int kg   = lane >> 4;              // 0..3
    int r0   = blockIdx.x * 64 + wave * 16;

    int gr = r0 + rowl; if (gr >= N_NODES) gr = N_NODES - 1;   // clamp loads
    const float* xrow = x + (size_t)gr * F_IN;
    const uint4* bf = reinterpret_cast<const uint4*>(bfrag);

    f32x4 acc[4];
    #pragma unroll
    for (int c = 0; c < 4; ++c) acc[c] = (f32x4){0.f, 0.f, 0.f, 0.f};

    #pragma unroll
    for (int kt = 0; kt < KTILES; ++kt) {
        int k0 = kt * 32 + kg * 8;
        float4 xa = make_float4(0.f, 0.f, 0.f, 0.f);
        float4 xb = make_float4(0.f, 0.f, 0.f, 0.f);
        if (k0 + 4 <= F_IN) xa = *reinterpret_cast<const float4*>(xrow + k0);
        if (k0 + 8 <= F_IN) xb = *reinterpret_cast<const float4*>(xrow + k0 + 4);
        half8 a;
        a[0] = (_Float16)xa.x; a[1] = (_Float16)xa.y;
        a[2] = (_Float16)xa.z; a[3] = (_Float16)xa.w;
        a[4] = (_Float16)xb.x; a[5] = (_Float16)xb.y;
        a[6] = (_Float16)xb.z; a[7] = (_Float16)xb.w;
        #pragma unroll
        for (int c = 0; c < 4; ++c) {
            union { uint4 u; half8 h; } bv;
            bv.u = bf[(size_t)(kt * 4 + c) * 64 + lane];
            acc[c] = __builtin_amdgcn_mfma_f32_16x16x32_f16(a, bv.h, acc[c], 0, 0, 0);
        }
    }

    // C/D layout: col = lane&15 (+16c), row = kg*4 + r
    #pragma unroll
    for (int c = 0; c < 4; ++c) {
        int col = c * 16 + rowl;
        float bias = b[col];
        #pragma unroll
        for (int r = 0; r < 4; ++r) {
            int grow = r0 + kg * 4 + r;
            if (grow < N_NODES) {
                float v = acc[c][r] + bias;
                size_t idx = (size_t)grow * H_DIM + col;
                x0[idx] = v;
                z [idx] = v;
                zH[idx] = __float2half(v);
            }
        }
    }
}

// ---------------- CSR build ----------------
__global__ void hist_kernel(const int* __restrict__ src, int* __restrict__ counts)
{
    int e = blockIdx.x * 256 + threadIdx.x;
    if (e < N_EDGES) atomicAdd(&counts[src[e]], 1);
}

__global__ __launch_bounds__(256) void scanA_kernel(
    const int* __restrict__ counts, int* __restrict__ blockSums)
{
    __shared__ int red[256];
    int i = blockIdx.x * 256 + threadIdx.x;
    red[threadIdx.x] = (i < N_NODES) ? counts[i] : 0;
    __syncthreads();
    #pragma unroll
    for (int s = 128; s > 0; s >>= 1) {
        if (threadIdx.x < s) red[threadIdx.x] += red[threadIdx.x + s];
        __syncthreads();
    }
    if (threadIdx.x == 0) blockSums[blockIdx.x] = red[0];
}

__global__ __launch_bounds__(256) void scanB_kernel(
    const int* __restrict__ blockSums, int* __restrict__ blockBases)
{
    __shared__ int s[256];
    int tid = threadIdx.x;
    int v = (tid < NB_SCAN) ? blockSums[tid] : 0;
    s[tid] = v;
    __syncthreads();
    #pragma unroll
    for (int d = 1; d < 256; d <<= 1) {
        int t = (tid >= d) ? s[tid - d] : 0;
        __syncthreads();
        s[tid] += t;
        __syncthreads();
    }
    if (tid < NB_SCAN) blockBases[tid] = s[tid] - v;
}

__global__ __launch_bounds__(256) void scanC_kernel(
    const int* __restrict__ counts, const int* __restrict__ blockBases,
    int* __restrict__ off, int* __restrict__ cursor)
{
    __shared__ int s[256];
    int tid = threadIdx.x;
    int i = blockIdx.x * 256 + tid;
    int v = (i < N_NODES) ? counts[i] : 0;
    s[tid] = v;
    __syncthreads();
    #pragma unroll
    for (int d = 1; d < 256; d <<= 1) {
        int t = (tid >= d) ? s[tid - d] : 0;
        __syncthreads();
        s[tid] += t;
        __syncthreads();
    }
    if (i < N_NODES) {
        int excl = blockBases[blockIdx.x] + s[tid] - v;
        off[i] = excl;
        cursor[i] = excl;
        if (i == N_NODES - 1) off[N_NODES] = excl + v;
    }
}

__global__ void scatter_kernel(const int* __restrict__ src, const int* __restrict__ dst,
                               const float* __restrict__ w,
                               int* __restrict__ cursor, int2* __restrict__ epack)
{
    int e = blockIdx.x * 256 + threadIdx.x;
    if (e < N_EDGES) {
        int s = src[e];
        int p = atomicAdd(&cursor[s], 1);
        epack[p] = make_int2(dst[e], __float_as_int(w[e]));
    }
}

// ---------------- Fused RK4 stage (fp16 gather + self, fp32 streams) -------
__global__ __launch_bounds__(256) void stage_kernel(
    const int* __restrict__ off, const int2* __restrict__ epack,
    const __half* __restrict__ zsH, const float* __restrict__ zb,
    const float* __restrict__ x0, const float* __restrict__ alpha,
    float* __restrict__ acc, __half* __restrict__ outH,
    float* __restrict__ outZ, int stage, float cnext)
{
    int node = blockIdx.x * 16 + (threadIdx.x >> 4);
    if (node >= N_NODES) return;
    int c = (threadIdx.x & 15) << 2;

    int jb = off[node], je = off[node + 1];
    float4 az0 = make_float4(0.f, 0.f, 0.f, 0.f);
    float4 az1 = make_float4(0.f, 0.f, 0.f, 0.f);
    float4 az2 = make_float4(0.f, 0.f, 0.f, 0.f);
    float4 az3 = make_float4(0.f, 0.f, 0.f, 0.f);

    union HC { uint2 u; __half2 h[2]; };

    int j = jb;
    for (; j + 3 < je; j += 4) {
        int2 e0 = epack[j];
        int2 e1 = epack[j + 1];
        int2 e2 = epack[j + 2];
        int2 e3 = epack[j + 3];
        HC r0, r1, r2, r3;
        r0.u = *reinterpret_cast<const uint2*>(zsH + (size_t)e0.x * H_DIM + c);
        r1.u = *reinterpret_cast<const uint2*>(zsH + (size_t)e1.x * H_DIM + c);
        r2.u = *reinterpret_cast<const uint2*>(zsH + (size_t)e2.x * H_DIM + c);
        r3.u = *reinterpret_cast<const uint2*>(zsH + (size_t)e3.x * H_DIM + c);
        float w0 = __int_as_float(e0.y), w1 = __int_as_float(e1.y);
        float w2 = __int_as_float(e2.y), w3 = __int_as_float(e3.y);
        float2 lo, hi;
        lo = __half22float2(r0.h[0]); hi = __half22float2(r0.h[1]);
        az0.x = fmaf(w0, lo.x, az0.x); az0.y = fmaf(w0, lo.y, az0.y);
        az0.z = fmaf(w0, hi.x, az0.z); az0.w = fmaf(w0, hi.y, az0.w);
        lo = __half22float2(r1.h[0]); hi = __half22float2(r1.h[1]);
        az1.x = fmaf(w1, lo.x, az1.x); az1.y = fmaf(w1, lo.y, az1.y);
        az1.z = fmaf(w1, hi.x, az1.z); az1.w = fmaf(w1, hi.y, az1.w);
        lo = __half22float2(r2.h[0]); hi = __half22float2(r2.h[1]);
        az2.x = fmaf(w2, lo.x, az2.x); az2.y = fmaf(w2, lo.y, az2.y);
        az2.z = fmaf(w2, hi.x, az2.z); az2.w = fmaf(w2, hi.y, az2.w);
        lo = __half22float2(r3.h[0]); hi = __half22float2(r3.h[1]);
        az3.x = fmaf(w3, lo.x, az3.x); az3.y = fmaf(w3, lo.y, az3.y);
        az3.z = fmaf(w3, hi.x, az3.z); az3.w = fmaf(w3, hi.y, az3.w);
    }
    for (; j < je; ++j) {
        int2 e0 = epack[j];
        HC r0;
        r0.u = *reinterpret_cast<const uint2*>(zsH + (size_t)e0.x * H_DIM + c);
        float w0 = __int_as_float(e0.y);
        float2 lo = __half22float2(r0.h[0]);
        float2 hi = __half22float2(r0.h[1]);
        az0.x = fmaf(w0, lo.x, az0.x); az0.y = fmaf(w0, lo.y, az0.y);
        az0.z = fmaf(w0, hi.x, az0.z); az0.w = fmaf(w0, hi.y, az0.w);
    }
    float4 az;
    az.x = (az0.x + az1.x) + (az2.x + az3.x);
    az.y = (az0.y + az1.y) + (az2.y + az3.y);
    az.z = (az0.z + az1.z) + (az2.z + az3.z);
    az.w = (az0.w + az1.w) + (az2.w + az3.w);

    size_t idx = (size_t)node * H_DIM + c;
    HC sr; sr.u = *reinterpret_cast<const uint2*>(zsH + idx);
    float2 slo = __half22float2(sr.h[0]);
    float2 shi = __half22float2(sr.h[1]);
    const float4 x0v = *reinterpret_cast<const float4*>(x0 + idx);
    float a = 0.5f / (1.f + __expf(-alpha[node]));

    float4 k;
    k.x = fmaf(a, az.x - slo.x, x0v.x);
    k.y = fmaf(a, az.y - slo.y, x0v.y);
    k.z = fmaf(a, az.z - shi.x, x0v.z);
    k.w = fmaf(a, az.w - shi.y, x0v.w);

    float4 zbv = *reinterpret_cast<const float4*>(zb + idx);
    float4 o;
    if (stage == 3) {
        float4 av = *reinterpret_cast<const float4*>(acc + idx);
        o.x = fmaf(cnext, av.x + k.x, zbv.x);
        o.y = fmaf(cnext, av.y + k.y, zbv.y);
        o.z = fmaf(cnext, av.z + k.z, zbv.z);
        o.w = fmaf(cnext, av.w + k.w, zbv.w);
        *reinterpret_cast<float4*>(outZ + idx) = o;
    } else {
        if (stage == 0) {
            *reinterpret_cast<float4*>(acc + idx) = k;
        } else {
            float4 av = *reinterpret_cast<const float4*>(acc + idx);
            av.x = fmaf(2.f, k.x, av.x);
            av.y = fmaf(2.f, k.y, av.y);
            av.z = fmaf(2.f, k.z, av.z);
            av.w = fmaf(2.f, k.w, av.w);
            *reinterpret_cast<float4*>(acc + idx) = av;
        }
        o.x = fmaf(cnext, k.x, zbv.x);
        o.y = fmaf(cnext, k.y, zbv.y);
        o.z = fmaf(cnext, k.z, zbv.z);
        o.w = fmaf(cnext, k.w, zbv.w);
    }
    HC sv;
    sv.h[0] = __float22half2_rn(make_float2(o.x, o.y));
    sv.h[1] = __float22half2_rn(make_float2(o.z, o.w));
    *reinterpret_cast<uint2*>(outH + idx) = sv.u;
}

// ---------------- Decoder: out = relu(z) @ m2_w + m2_b ----------------
__global__ __launch_bounds__(256) void decoder_kernel(
    const float* __restrict__ z, const float* __restrict__ W2,
    const float* __restrict__ b2, float* __restrict__ out)
{
    __shared__ float zsm[4][H_DIM];
    int lane = threadIdx.x & 63;
    int w    = threadIdx.x >> 6;
    int node = blockIdx.x * 4 + w;
    int ld   = node >= N_NODES ? N_NODES - 1 : node;
    float zv = z[(size_t)ld * H_DIM + lane];
    zsm[w][lane] = zv > 0.f ? zv : 0.f;
    __syncthreads();
    if (node < N_NODES && lane < C_OUT) {
        float acc = b2[lane];
        #pragma unroll
        for (int k = 0; k < H_DIM; ++k)
            acc = fmaf(zsm[w][k], W2[k * C_OUT + lane], acc);
        out[(size_t)node * C_OUT + lane] = acc;
    }
}

extern "C" void kernel_launch(void* const* d_in, const int* in_sizes, int n_in,
                              void* d_out, int out_size, void* d_ws, size_t ws_size,
                              hipStream_t stream)
{
    const float* x     = (const float*)d_in[0];
    const float* ew    = (const float*)d_in[1];
    const float* m1w   = (const float*)d_in[2];
    const float* m1b   = (const float*)d_in[3];
    const float* alpha = (const float*)d_in[4];
    const float* m2w   = (const float*)d_in[5];
    const float* m2b   = (const float*)d_in[6];
    const int*   esrc  = (const int*)d_in[7];
    const int*   edst  = (const int*)d_in[8];
    float* out = (float*)d_out;

    char* ws = (char*)d_ws;
    size_t o = 0;
    auto alloc = [&](size_t bytes) -> void* {
        void* p = ws + o;
        o = (o + bytes + 255) & ~(size_t)255;
        return p;
    };
    float*  x0     = (float*)alloc((size_t)N_NODES * H_DIM * 4);
    float*  z      = (float*)alloc((size_t)N_NODES * H_DIM * 4);
    float*  acc    = (float*)alloc((size_t)N_NODES * H_DIM * 4);
    __half* zH     = (__half*)alloc((size_t)N_NODES * H_DIM * 2);
    __half* ztAH   = (__half*)alloc((size_t)N_NODES * H_DIM * 2);
    __half* ztBH   = (__half*)alloc((size_t)N_NODES * H_DIM * 2);
    __half* bfrag  = (__half*)alloc((size_t)KTILES * 4 * 64 * 8 * 2);
    int*    counts = (int*)alloc((size_t)N_NODES * 4);
    int*    off    = (int*)alloc((size_t)(N_NODES + 1) * 4);
    int*    cursor = (int*)alloc((size_t)N_NODES * 4);
    int*    bsums  = (int*)alloc((size_t)NB_SCAN * 4);
    int*    bbases = (int*)alloc((size_t)NB_SCAN * 4);
    int2*   epack  = (int2*)alloc((size_t)N_EDGES * 8);

    hipMemsetAsync(counts, 0, (size_t)N_NODES * 4, stream);
    hist_kernel<<<(N_EDGES + 255) / 256, 256, 0, stream>>>(esrc, counts);
    scanA_kernel<<<NB_SCAN, 256, 0, stream>>>(counts, bsums);
    scanB_kernel<<<1, 256, 0, stream>>>(bsums, bbases);
    scanC_kernel<<<NB_SCAN, 256, 0, stream>>>(counts, bbases, off, cursor);
    scatter_kernel<<<(N_EDGES + 255) / 256, 256, 0, stream>>>(esrc, edst, ew, cursor, epack);

    bfrag_kernel<<<(KTILES * 4 * 64 + 255) / 256, 256, 0, stream>>>(m1w, bfrag);
    encoder_kernel<<<(N_NODES + 63) / 64, 256, 0, stream>>>(x, bfrag, m1b, x0, z, zH);

    const float dt = 1.0f / STEPS;
    int sgrid = (N_NODES + 15) / 16;
    for (int step = 0; step < STEPS; ++step) {
        stage_kernel<<<sgrid, 256, 0, stream>>>(off, epack, zH,   z, x0, alpha, acc, ztAH, nullptr, 0, 0.5f * dt);
        stage_kernel<<<sgrid, 256, 0, stream>>>(off, epack, ztAH, z, x0, alpha, acc, ztBH, nullptr, 1, 0.5f * dt);
        stage_kernel<<<sgrid, 256, 0, stream>>>(off, epack, ztBH, z, x0, alpha, acc, ztAH, nullptr, 2, dt);
        stage_kernel<<<sgrid, 256, 0, stream>>>(off, epack, ztAH, z, x0, alpha, acc, zH,   z,       3, dt / 6.0f);
    }

    decoder_kernel<<<(N_NODES + 3) / 4, 256, 0, stream>>>(z, m2w, m2b, out);
}

// Round 7
// 453.009 us; speedup vs baseline: 1.4646x; 1.0803x over previous
//
#include <hip/hip_runtime.h>
#include <hip/hip_fp16.h>

#define N_NODES 50000
#define N_EDGES 600000
#define F_IN    500
#define H_DIM   64
#define C_OUT   40
#define STEPS   4
#define NB_SCAN ((N_NODES + 255) / 256)   // 196
#define KTILES  16                        // 512 k padded, 32 per MFMA

using half8 = __attribute__((ext_vector_type(8))) _Float16;
using f32x4 = __attribute__((ext_vector_type(4))) float;

// ---------------- B-fragment precompute: W (500x64 f32) -> MFMA frags ------
__global__ __launch_bounds__(256) void bfrag_kernel(
    const float* __restrict__ W, __half* __restrict__ bfrag)
{
    int t = blockIdx.x * 256 + threadIdx.x;
    if (t >= KTILES * 4 * 64) return;
    int lane = t & 63;
    int c    = (t >> 6) & 3;
    int kt   = t >> 8;
    int col  = c * 16 + (lane & 15);
    int kb   = kt * 32 + (lane >> 4) * 8;
    union { uint4 u; __half h[8]; } v;
    #pragma unroll
    for (int j = 0; j < 8; ++j) {
        int k = kb + j;
        v.h[j] = (k < F_IN) ? __float2half(W[(size_t)k * H_DIM + col]) : __half(0.f);
    }
    *reinterpret_cast<uint4*>(bfrag + (size_t)t * 8) = v.u;
}

// ---------------- Encoder: MFMA GEMM, K split across wave pairs -----------
// Block = 256 thr = 4 waves = 2 pairs; pair p owns rows blockIdx*32 + p*16
// + 16; within a pair, wave-half h does KTILES h*8..h*8+7. LDS reduce.
__global__ __launch_bounds__(256) void encoder_kernel(
    const float* __restrict__ x, const __half* __restrict__ bfrag,
    const float* __restrict__ b, __half* __restrict__ x0H,
    float* __restrict__ zF, __half* __restrict__ zH)
{
    __shared__ f32x4 red[2][64][4];   // 8 KB

    int wave = threadIdx.x >> 6;
    int lane = threadIdx.x & 63;
    int pair = wave >> 1;
    int half = wave & 1;
    int rowl = lane & 15;
    int kg   = lane >> 4;              // 0..3
    int r0   = blockIdx.x * 32 + pair * 16;

    int gr = r0 + rowl; if (gr >= N_NODES) gr = N_NODES - 1;   // clamp loads
    const float* xrow = x + (size_t)gr * F_IN;
    const uint4* bf = reinterpret_cast<const uint4*>(bfrag);

    f32x4 acc[4];
    #pragma unroll
    for (int c = 0; c < 4; ++c) acc[c] = (f32x4){0.f, 0.f, 0.f, 0.f};

    int ktb = half * 8;
    #pragma unroll
    for (int ki = 0; ki < 8; ++ki) {
        int kt = ktb + ki;
        int k0 = kt * 32 + kg * 8;
        float4 xa = make_float4(0.f, 0.f, 0.f, 0.f);
        float4 xb = make_float4(0.f, 0.f, 0.f, 0.f);
        if (k0 + 4 <= F_IN) xa = *reinterpret_cast<const float4*>(xrow + k0);
        if (k0 + 8 <= F_IN) xb = *reinterpret_cast<const float4*>(xrow + k0 + 4);
        half8 a;
        a[0] = (_Float16)xa.x; a[1] = (_Float16)xa.y;
        a[2] = (_Float16)xa.z; a[3] = (_Float16)xa.w;
        a[4] = (_Float16)xb.x; a[5] = (_Float16)xb.y;
        a[6] = (_Float16)xb.z; a[7] = (_Float16)xb.w;
        #pragma unroll
        for (int c = 0; c < 4; ++c) {
            union { uint4 u; half8 h; } bv;
            bv.u = bf[(size_t)(kt * 4 + c) * 64 + lane];
            acc[c] = __builtin_amdgcn_mfma_f32_16x16x32_f16(a, bv.h, acc[c], 0, 0, 0);
        }
    }

    if (half == 1) {
        #pragma unroll
        for (int c = 0; c < 4; ++c) red[pair][lane][c] = acc[c];
    }
    __syncthreads();
    if (half == 0) {
        #pragma unroll
        for (int c = 0; c < 4; ++c) {
            f32x4 r = red[pair][lane][c];
            acc[c][0] += r[0]; acc[c][1] += r[1];
            acc[c][2] += r[2]; acc[c][3] += r[3];
        }
        // C/D layout: col = lane&15 (+16c), row = kg*4 + r
        #pragma unroll
        for (int c = 0; c < 4; ++c) {
            int col = c * 16 + rowl;
            float bias = b[col];
            #pragma unroll
            for (int r = 0; r < 4; ++r) {
                int grow = r0 + kg * 4 + r;
                if (grow < N_NODES) {
                    float v = acc[c][r] + bias;
                    size_t idx = (size_t)grow * H_DIM + col;
                    zF[idx]  = v;
                    __half hv = __float2half(v);
                    zH[idx]  = hv;
                    x0H[idx] = hv;
                }
            }
        }
    }
}

// ---------------- CSR build ----------------
__global__ void hist_kernel(const int* __restrict__ src, int* __restrict__ counts)
{
    int e = blockIdx.x * 256 + threadIdx.x;
    if (e < N_EDGES) atomicAdd(&counts[src[e]], 1);
}

__global__ __launch_bounds__(256) void scanA_kernel(
    const int* __restrict__ counts, int* __restrict__ blockSums)
{
    __shared__ int red[256];
    int i = blockIdx.x * 256 + threadIdx.x;
    red[threadIdx.x] = (i < N_NODES) ? counts[i] : 0;
    __syncthreads();
    #pragma unroll
    for (int s = 128; s > 0; s >>= 1) {
        if (threadIdx.x < s) red[threadIdx.x] += red[threadIdx.x + s];
        __syncthreads();
    }
    if (threadIdx.x == 0) blockSums[blockIdx.x] = red[0];
}

__global__ __launch_bounds__(256) void scanB_kernel(
    const int* __restrict__ blockSums, int* __restrict__ blockBases)
{
    __shared__ int s[256];
    int tid = threadIdx.x;
    int v = (tid < NB_SCAN) ? blockSums[tid] : 0;
    s[tid] = v;
    __syncthreads();
    #pragma unroll
    for (int d = 1; d < 256; d <<= 1) {
        int t = (tid >= d) ? s[tid - d] : 0;
        __syncthreads();
        s[tid] += t;
        __syncthreads();
    }
    if (tid < NB_SCAN) blockBases[tid] = s[tid] - v;
}

__global__ __launch_bounds__(256) void scanC_kernel(
    const int* __restrict__ counts, const int* __restrict__ blockBases,
    int* __restrict__ off, int* __restrict__ cursor)
{
    __shared__ int s[256];
    int tid = threadIdx.x;
    int i = blockIdx.x * 256 + tid;
    int v = (i < N_NODES) ? counts[i] : 0;
    s[tid] = v;
    __syncthreads();
    #pragma unroll
    for (int d = 1; d < 256; d <<= 1) {
        int t = (tid >= d) ? s[tid - d] : 0;
        __syncthreads();
        s[tid] += t;
        __syncthreads();
    }
    if (i < N_NODES) {
        int excl = blockBases[blockIdx.x] + s[tid] - v;
        off[i] = excl;
        cursor[i] = excl;
        if (i == N_NODES - 1) off[N_NODES] = excl + v;
    }
}

__global__ void scatter_kernel(const int* __restrict__ src, const int* __restrict__ dst,
                               const float* __restrict__ w,
                               int* __restrict__ cursor, int2* __restrict__ epack)
{
    int e = blockIdx.x * 256 + threadIdx.x;
    if (e < N_EDGES) {
        int s = src[e];
        int p = atomicAdd(&cursor[s], 1);
        epack[p] = make_int2(dst[e], __float_as_int(w[e]));
    }
}

// ---------------- Fused RK4 stage (all-fp16 streams except stage-3 z) ------
// STAGE 0: base = self (zsH == zH); accH = k
// STAGE 1/2: base = zH; accH += 2k
// STAGE 3: o = zbF + cnext*(accH + k) -> outZ (fp32) + outH (fp16 = zH)
template<int STAGE>
__global__ __launch_bounds__(256) void stage_kernel(
    const int* __restrict__ off, const int2* __restrict__ epack,
    const __half* __restrict__ zsH, const __half* __restrict__ zH,
    const float* __restrict__ zbF, const __half* __restrict__ x0H,
    const float* __restrict__ alpha, __half* __restrict__ accH,
    __half* __restrict__ outH, float* __restrict__ outZ, float cnext)
{
    int node = blockIdx.x * 16 + (threadIdx.x >> 4);
    if (node >= N_NODES) return;
    int c = (threadIdx.x & 15) << 2;

    int jb = off[node], je = off[node + 1];
    float4 az0 = make_float4(0.f, 0.f, 0.f, 0.f);
    float4 az1 = make_float4(0.f, 0.f, 0.f, 0.f);
    float4 az2 = make_float4(0.f, 0.f, 0.f, 0.f);
    float4 az3 = make_float4(0.f, 0.f, 0.f, 0.f);

    union HC { uint2 u; __half2 h[2]; };

    int j = jb;
    for (; j + 3 < je; j += 4) {
        int2 e0 = epack[j];
        int2 e1 = epack[j + 1];
        int2 e2 = epack[j + 2];
        int2 e3 = epack[j + 3];
        HC r0, r1, r2, r3;
        r0.u = *reinterpret_cast<const uint2*>(zsH + (size_t)e0.x * H_DIM + c);
        r1.u = *reinterpret_cast<const uint2*>(zsH + (size_t)e1.x * H_DIM + c);
        r2.u = *reinterpret_cast<const uint2*>(zsH + (size_t)e2.x * H_DIM + c);
        r3.u = *reinterpret_cast<const uint2*>(zsH + (size_t)e3.x * H_DIM + c);
        float w0 = __int_as_float(e0.y), w1 = __int_as_float(e1.y);
        float w2 = __int_as_float(e2.y), w3 = __int_as_float(e3.y);
        float2 lo, hi;
        lo = __half22float2(r0.h[0]); hi = __half22float2(r0.h[1]);
        az0.x = fmaf(w0, lo.x, az0.x); az0.y = fmaf(w0, lo.y, az0.y);
        az0.z = fmaf(w0, hi.x, az0.z); az0.w = fmaf(w0, hi.y, az0.w);
        lo = __half22float2(r1.h[0]); hi = __half22float2(r1.h[1]);
        az1.x = fmaf(w1, lo.x, az1.x); az1.y = fmaf(w1, lo.y, az1.y);
        az1.z = fmaf(w1, hi.x, az1.z); az1.w = fmaf(w1, hi.y, az1.w);
        lo = __half22float2(r2.h[0]); hi = __half22float2(r2.h[1]);
        az2.x = fmaf(w2, lo.x, az2.x); az2.y = fmaf(w2, lo.y, az2.y);
        az2.z = fmaf(w2, hi.x, az2.z); az2.w = fmaf(w2, hi.y, az2.w);
        lo = __half22float2(r3.h[0]); hi = __half22float2(r3.h[1]);
        az3.x = fmaf(w3, lo.x, az3.x); az3.y = fmaf(w3, lo.y, az3.y);
        az3.z = fmaf(w3, hi.x, az3.z); az3.w = fmaf(w3, hi.y, az3.w);
    }
    for (; j < je; ++j) {
        int2 e0 = epack[j];
        HC r0;
        r0.u = *reinterpret_cast<const uint2*>(zsH + (size_t)e0.x * H_DIM + c);
        float w0 = __int_as_float(e0.y);
        float2 lo = __half22float2(r0.h[0]);
        float2 hi = __half22float2(r0.h[1]);
        az0.x = fmaf(w0, lo.x, az0.x); az0.y = fmaf(w0, lo.y, az0.y);
        az0.z = fmaf(w0, hi.x, az0.z); az0.w = fmaf(w0, hi.y, az0.w);
    }
    float4 az;
    az.x = (az0.x + az1.x) + (az2.x + az3.x);
    az.y = (az0.y + az1.y) + (az2.y + az3.y);
    az.z = (az0.z + az1.z) + (az2.z + az3.z);
    az.w = (az0.w + az1.w) + (az2.w + az3.w);

    size_t idx = (size_t)node * H_DIM + c;
    HC sr; sr.u = *reinterpret_cast<const uint2*>(zsH + idx);
    float2 slo = __half22float2(sr.h[0]);
    float2 shi = __half22float2(sr.h[1]);
    HC xr; xr.u = *reinterpret_cast<const uint2*>(x0H + idx);
    float2 xlo = __half22float2(xr.h[0]);
    float2 xhi = __half22float2(xr.h[1]);
    float a = 0.5f / (1.f + __expf(-alpha[node]));

    float4 k;
    k.x = fmaf(a, az.x - slo.x, xlo.x);
    k.y = fmaf(a, az.y - slo.y, xlo.y);
    k.z = fmaf(a, az.z - shi.x, xhi.x);
    k.w = fmaf(a, az.w - shi.y, xhi.y);

    float4 o;
    if constexpr (STAGE == 0) {
        HC av;
        av.h[0] = __float22half2_rn(make_float2(k.x, k.y));
        av.h[1] = __float22half2_rn(make_float2(k.z, k.w));
        *reinterpret_cast<uint2*>(accH + idx) = av.u;
        o.x = fmaf(cnext, k.x, slo.x);
        o.y = fmaf(cnext, k.y, slo.y);
        o.z = fmaf(cnext, k.z, shi.x);
        o.w = fmaf(cnext, k.w, shi.y);
    } else if constexpr (STAGE == 1 || STAGE == 2) {
        HC ar; ar.u = *reinterpret_cast<const uint2*>(accH + idx);
        float2 alo = __half22float2(ar.h[0]);
        float2 ahi = __half22float2(ar.h[1]);
        alo.x = fmaf(2.f, k.x, alo.x); alo.y = fmaf(2.f, k.y, alo.y);
        ahi.x = fmaf(2.f, k.z, ahi.x); ahi.y = fmaf(2.f, k.w, ahi.y);
        HC aw;
        aw.h[0] = __float22half2_rn(alo);
        aw.h[1] = __float22half2_rn(ahi);
        *reinterpret_cast<uint2*>(accH + idx) = aw.u;
        HC br; br.u = *reinterpret_cast<const uint2*>(zH + idx);
        float2 blo = __half22float2(br.h[0]);
        float2 bhi = __half22float2(br.h[1]);
        o.x = fmaf(cnext, k.x, blo.x);
        o.y = fmaf(cnext, k.y, blo.y);
        o.z = fmaf(cnext, k.z, bhi.x);
        o.w = fmaf(cnext, k.w, bhi.y);
    } else {
        HC ar; ar.u = *reinterpret_cast<const uint2*>(accH + idx);
        float2 alo = __half22float2(ar.h[0]);
        float2 ahi = __half22float2(ar.h[1]);
        float4 zb4 = *reinterpret_cast<const float4*>(zbF + idx);
        o.x = fmaf(cnext, alo.x + k.x, zb4.x);
        o.y = fmaf(cnext, alo.y + k.y, zb4.y);
        o.z = fmaf(cnext, ahi.x + k.z, zb4.z);
        o.w = fmaf(cnext, ahi.y + k.w, zb4.w);
        *reinterpret_cast<float4*>(outZ + idx) = o;
    }
    HC sv;
    sv.h[0] = __float22half2_rn(make_float2(o.x, o.y));
    sv.h[1] = __float22half2_rn(make_float2(o.z, o.w));
    *reinterpret_cast<uint2*>(outH + idx) = sv.u;
}

// ---------------- Decoder: out = relu(z) @ m2_w + m2_b ----------------
__global__ __launch_bounds__(256) void decoder_kernel(
    const float* __restrict__ z, const float* __restrict__ W2,
    const float* __restrict__ b2, float* __restrict__ out)
{
    __shared__ float zsm[4][H_DIM];
    int lane = threadIdx.x & 63;
    int w    = threadIdx.x >> 6;
    int node = blockIdx.x * 4 + w;
    int ld   = node >= N_NODES ? N_NODES - 1 : node;
    float zv = z[(size_t)ld * H_DIM + lane];
    zsm[w][lane] = zv > 0.f ? zv : 0.f;
    __syncthreads();
    if (node < N_NODES && lane < C_OUT) {
        float acc = b2[lane];
        #pragma unroll
        for (int k = 0; k < H_DIM; ++k)
            acc = fmaf(zsm[w][k], W2[k * C_OUT + lane], acc);
        out[(size_t)node * C_OUT + lane] = acc;
    }
}

extern "C" void kernel_launch(void* const* d_in, const int* in_sizes, int n_in,
                              void* d_out, int out_size, void* d_ws, size_t ws_size,
                              hipStream_t stream)
{
    const float* x     = (const float*)d_in[0];
    const float* ew    = (const float*)d_in[1];
    const float* m1w   = (const float*)d_in[2];
    const float* m1b   = (const float*)d_in[3];
    const float* alpha = (const float*)d_in[4];
    const float* m2w   = (const float*)d_in[5];
    const float* m2b   = (const float*)d_in[6];
    const int*   esrc  = (const int*)d_in[7];
    const int*   edst  = (const int*)d_in[8];
    float* out = (float*)d_out;

    char* ws = (char*)d_ws;
    size_t o = 0;
    auto alloc = [&](size_t bytes) -> void* {
        void* p = ws + o;
        o = (o + bytes + 255) & ~(size_t)255;
        return p;
    };
    float*  z      = (float*)alloc((size_t)N_NODES * H_DIM * 4);
    __half* x0H    = (__half*)alloc((size_t)N_NODES * H_DIM * 2);
    __half* zH     = (__half*)alloc((size_t)N_NODES * H_DIM * 2);
    __half* ztAH   = (__half*)alloc((size_t)N_NODES * H_DIM * 2);
    __half* ztBH   = (__half*)alloc((size_t)N_NODES * H_DIM * 2);
    __half* accH   = (__half*)alloc((size_t)N_NODES * H_DIM * 2);
    __half* bfrag  = (__half*)alloc((size_t)KTILES * 4 * 64 * 8 * 2);
    int*    counts = (int*)alloc((size_t)N_NODES * 4);
    int*    off    = (int*)alloc((size_t)(N_NODES + 1) * 4);
    int*    cursor = (int*)alloc((size_t)N_NODES * 4);
    int*    bsums  = (int*)alloc((size_t)NB_SCAN * 4);
    int*    bbases = (int*)alloc((size_t)NB_SCAN * 4);
    int2*   epack  = (int2*)alloc((size_t)N_EDGES * 8);

    hipMemsetAsync(counts, 0, (size_t)N_NODES * 4, stream);
    hist_kernel<<<(N_EDGES + 255) / 256, 256, 0, stream>>>(esrc, counts);
    scanA_kernel<<<NB_SCAN, 256, 0, stream>>>(counts, bsums);
    scanB_kernel<<<1, 256, 0, stream>>>(bsums, bbases);
    scanC_kernel<<<NB_SCAN, 256, 0, stream>>>(counts, bbases, off, cursor);
    scatter_kernel<<<(N_EDGES + 255) / 256, 256, 0, stream>>>(esrc, edst, ew, cursor, epack);

    bfrag_kernel<<<(KTILES * 4 * 64 + 255) / 256, 256, 0, stream>>>(m1w, bfrag);
    encoder_kernel<<<(N_NODES + 31) / 32, 256, 0, stream>>>(x, bfrag, m1b, x0H, z, zH);

    const float dt = 1.0f / STEPS;
    int sgrid = (N_NODES + 15) / 16;
    for (int step = 0; step < STEPS; ++step) {
        stage_kernel<0><<<sgrid, 256, 0, stream>>>(off, epack, zH,   zH, nullptr, x0H, alpha, accH, ztAH, nullptr, 0.5f * dt);
        stage_kernel<1><<<sgrid, 256, 0, stream>>>(off, epack, ztAH, zH, nullptr, x0H, alpha, accH, ztBH, nullptr, 0.5f * dt);
        stage_kernel<2><<<sgrid, 256, 0, stream>>>(off, epack, ztBH, zH, nullptr, x0H, alpha, accH, ztAH, nullptr, dt);
        stage_kernel<3><<<sgrid, 256, 0, stream>>>(off, epack, ztAH, zH, z,       x0H, alpha, accH, zH,   z,       dt / 6.0f);
    }

    decoder_kernel<<<(N_NODES + 3) / 4, 256, 0, stream>>>(z, m2w, m2b, out);
}

// Round 9
// 393.680 us; speedup vs baseline: 1.6854x; 1.1507x over previous
//
#include <hip/hip_runtime.h>
#include <hip/hip_fp16.h>

#define N_NODES 50000
#define N_EDGES 600000
#define F_IN    500
#define H_DIM   64
#define C_OUT   40
#define STEPS   4
#define NB_SCAN ((N_NODES + 255) / 256)   // 196
#define KTILES  16                        // 512 k padded, 32 per MFMA

using half8 = __attribute__((ext_vector_type(8))) _Float16;
using f32x4 = __attribute__((ext_vector_type(4))) float;

// ---------------- B-fragment precompute: W (500x64 f32) -> MFMA frags ------
__global__ __launch_bounds__(256) void bfrag_kernel(
    const float* __restrict__ W, __half* __restrict__ bfrag)
{
    int t = blockIdx.x * 256 + threadIdx.x;
    if (t >= KTILES * 4 * 64) return;
    int lane = t & 63;
    int c    = (t >> 6) & 3;
    int kt   = t >> 8;
    int col  = c * 16 + (lane & 15);
    int kb   = kt * 32 + (lane >> 4) * 8;
    union { uint4 u; __half h[8]; } v;
    #pragma unroll
    for (int j = 0; j < 8; ++j) {
        int k = kb + j;
        v.h[j] = (k < F_IN) ? __float2half(W[(size_t)k * H_DIM + col]) : __half(0.f);
    }
    *reinterpret_cast<uint4*>(bfrag + (size_t)t * 8) = v.u;
}

// ---------------- Encoder: MFMA GEMM, K-split pairs + full x prefetch ------
__global__ __launch_bounds__(256) void encoder_kernel(
    const float* __restrict__ x, const __half* __restrict__ bfrag,
    const float* __restrict__ b, __half* __restrict__ x0H,
    float* __restrict__ zF, __half* __restrict__ zH)
{
    __shared__ f32x4 red[2][64][4];   // 8 KB

    int wave = threadIdx.x >> 6;
    int lane = threadIdx.x & 63;
    int pair = wave >> 1;
    int half = wave & 1;
    int rowl = lane & 15;
    int kg   = lane >> 4;              // 0..3
    int r0   = blockIdx.x * 32 + pair * 16;

    int gr = r0 + rowl; if (gr >= N_NODES) gr = N_NODES - 1;
    const float* xrow = x + (size_t)gr * F_IN;
    const uint4* bf = reinterpret_cast<const uint4*>(bfrag);

    int ktb = half * 8;

    float4 xv[16];
    #pragma unroll
    for (int ki = 0; ki < 8; ++ki) {
        int k0 = (ktb + ki) * 32 + kg * 8;
        xv[2 * ki]     = make_float4(0.f, 0.f, 0.f, 0.f);
        xv[2 * ki + 1] = make_float4(0.f, 0.f, 0.f, 0.f);
        if (k0 + 4 <= F_IN) xv[2 * ki]     = *reinterpret_cast<const float4*>(xrow + k0);
        if (k0 + 8 <= F_IN) xv[2 * ki + 1] = *reinterpret_cast<const float4*>(xrow + k0 + 4);
    }

    f32x4 acc[4];
    #pragma unroll
    for (int c = 0; c < 4; ++c) acc[c] = (f32x4){0.f, 0.f, 0.f, 0.f};

    #pragma unroll
    for (int ki = 0; ki < 8; ++ki) {
        int kt = ktb + ki;
        float4 xa = xv[2 * ki], xb = xv[2 * ki + 1];
        half8 a;
        a[0] = (_Float16)xa.x; a[1] = (_Float16)xa.y;
        a[2] = (_Float16)xa.z; a[3] = (_Float16)xa.w;
        a[4] = (_Float16)xb.x; a[5] = (_Float16)xb.y;
        a[6] = (_Float16)xb.z; a[7] = (_Float16)xb.w;
        #pragma unroll
        for (int c = 0; c < 4; ++c) {
            union { uint4 u; half8 h; } bv;
            bv.u = bf[(size_t)(kt * 4 + c) * 64 + lane];
            acc[c] = __builtin_amdgcn_mfma_f32_16x16x32_f16(a, bv.h, acc[c], 0, 0, 0);
        }
    }

    if (half == 1) {
        #pragma unroll
        for (int c = 0; c < 4; ++c) red[pair][lane][c] = acc[c];
    }
    __syncthreads();
    if (half == 0) {
        #pragma unroll
        for (int c = 0; c < 4; ++c) {
            f32x4 r = red[pair][lane][c];
            acc[c][0] += r[0]; acc[c][1] += r[1];
            acc[c][2] += r[2]; acc[c][3] += r[3];
        }
        #pragma unroll
        for (int c = 0; c < 4; ++c) {
            int col = c * 16 + rowl;
            float bias = b[col];
            #pragma unroll
            for (int r = 0; r < 4; ++r) {
                int grow = r0 + kg * 4 + r;
                if (grow < N_NODES) {
                    float v = acc[c][r] + bias;
                    size_t idx = (size_t)grow * H_DIM + col;
                    zF[idx]  = v;
                    __half hv = __float2half(v);
                    zH[idx]  = hv;
                    x0H[idx] = hv;
                }
            }
        }
    }
}

// ---------------- CSR build ----------------
__global__ void hist_kernel(const int* __restrict__ src, int* __restrict__ counts)
{
    int e = blockIdx.x * 256 + threadIdx.x;
    if (e < N_EDGES) atomicAdd(&counts[src[e]], 1);
}

__global__ __launch_bounds__(256) void scanA_kernel(
    const int* __restrict__ counts, int* __restrict__ blockSums)
{
    __shared__ int red[256];
    int i = blockIdx.x * 256 + threadIdx.x;
    red[threadIdx.x] = (i < N_NODES) ? counts[i] : 0;
    __syncthreads();
    #pragma unroll
    for (int s = 128; s > 0; s >>= 1) {
        if (threadIdx.x < s) red[threadIdx.x] += red[threadIdx.x + s];
        __syncthreads();
    }
    if (threadIdx.x == 0) blockSums[blockIdx.x] = red[0];
}

__global__ __launch_bounds__(256) void scanB_kernel(
    const int* __restrict__ blockSums, int* __restrict__ blockBases)
{
    __shared__ int s[256];
    int tid = threadIdx.x;
    int v = (tid < NB_SCAN) ? blockSums[tid] : 0;
    s[tid] = v;
    __syncthreads();
    #pragma unroll
    for (int d = 1; d < 256; d <<= 1) {
        int t = (tid >= d) ? s[tid - d] : 0;
        __syncthreads();
        s[tid] += t;
        __syncthreads();
    }
    if (tid < NB_SCAN) blockBases[tid] = s[tid] - v;
}

__global__ __launch_bounds__(256) void scanC_kernel(
    const int* __restrict__ counts, const int* __restrict__ blockBases,
    int* __restrict__ off, int* __restrict__ cursor)
{
    __shared__ int s[256];
    int tid = threadIdx.x;
    int i = blockIdx.x * 256 + tid;
    int v = (i < N_NODES) ? counts[i] : 0;
    s[tid] = v;
    __syncthreads();
    #pragma unroll
    for (int d = 1; d < 256; d <<= 1) {
        int t = (tid >= d) ? s[tid - d] : 0;
        __syncthreads();
        s[tid] += t;
        __syncthreads();
    }
    if (i < N_NODES) {
        int excl = blockBases[blockIdx.x] + s[tid] - v;
        off[i] = excl;
        cursor[i] = excl;
        if (i == N_NODES - 1) off[N_NODES] = excl + v;
    }
}

__global__ void scatter_kernel(const int* __restrict__ src, const int* __restrict__ dst,
                               const float* __restrict__ w,
                               int* __restrict__ cursor, int2* __restrict__ epack)
{
    int e = blockIdx.x * 256 + threadIdx.x;
    if (e < N_EDGES) {
        int s = src[e];
        int p = atomicAdd(&cursor[s], 1);
        epack[p] = make_int2(dst[e], __float_as_int(w[e]));
    }
}

// ---------------- Fused RK4 stage: 8-lane groups, 32 gathers in flight -----
// Each lane owns 8 fp16 cols (uint4). 32 nodes/block.
// STAGE 0: base = self (zsH == zH); accH = k
// STAGE 1/2: base = zH; accH += 2k
// STAGE 3: o = zbF + cnext*(accH + k) -> outZ (fp32) + outH (fp16 = zH)
template<int STAGE>
__global__ __launch_bounds__(256) void stage_kernel(
    const int* __restrict__ off, const int2* __restrict__ epack,
    const __half* __restrict__ zsH, const __half* __restrict__ zH,
    const float* __restrict__ zbF, const __half* __restrict__ x0H,
    const float* __restrict__ alpha, __half* __restrict__ accH,
    __half* __restrict__ outH, float* __restrict__ outZ, float cnext)
{
    int node = blockIdx.x * 32 + (threadIdx.x >> 3);
    if (node >= N_NODES) return;
    int c = (threadIdx.x & 7) << 3;   // 8 fp16 cols per lane

    int jb = off[node], je = off[node + 1];

    union H4 { uint4 u; __half2 h[4]; };

    float azA[8], azB[8];
    #pragma unroll
    for (int i = 0; i < 8; ++i) { azA[i] = 0.f; azB[i] = 0.f; }

#define ACC8(dst, V, W)                                                    \
    {                                                                      \
        float2 f0 = __half22float2((V).h[0]);                              \
        float2 f1 = __half22float2((V).h[1]);                              \
        float2 f2 = __half22float2((V).h[2]);                              \
        float2 f3 = __half22float2((V).h[3]);                              \
        dst[0] = fmaf(W, f0.x, dst[0]); dst[1] = fmaf(W, f0.y, dst[1]);    \
        dst[2] = fmaf(W, f1.x, dst[2]); dst[3] = fmaf(W, f1.y, dst[3]);    \
        dst[4] = fmaf(W, f2.x, dst[4]); dst[5] = fmaf(W, f2.y, dst[5]);    \
        dst[6] = fmaf(W, f3.x, dst[6]); dst[7] = fmaf(W, f3.y, dst[7]);    \
    }

    int j = jb;
    for (; j + 3 < je; j += 4) {
        int2 e0 = epack[j];
        int2 e1 = epack[j + 1];
        int2 e2 = epack[j + 2];
        int2 e3 = epack[j + 3];
        H4 v0, v1, v2, v3;
        v0.u = *reinterpret_cast<const uint4*>(zsH + (size_t)e0.x * H_DIM + c);
        v1.u = *reinterpret_cast<const uint4*>(zsH + (size_t)e1.x * H_DIM + c);
        v2.u = *reinterpret_cast<const uint4*>(zsH + (size_t)e2.x * H_DIM + c);
        v3.u = *reinterpret_cast<const uint4*>(zsH + (size_t)e3.x * H_DIM + c);
        float w0 = __int_as_float(e0.y), w1 = __int_as_float(e1.y);
        float w2 = __int_as_float(e2.y), w3 = __int_as_float(e3.y);
        ACC8(azA, v0, w0);
        ACC8(azB, v1, w1);
        ACC8(azA, v2, w2);
        ACC8(azB, v3, w3);
    }
    for (; j < je; ++j) {
        int2 e0 = epack[j];
        H4 v0;
        v0.u = *reinterpret_cast<const uint4*>(zsH + (size_t)e0.x * H_DIM + c);
        float w0 = __int_as_float(e0.y);
        ACC8(azA, v0, w0);
    }
#undef ACC8

    float az[8];
    #pragma unroll
    for (int i = 0; i < 8; ++i) az[i] = azA[i] + azB[i];

    size_t idx = (size_t)node * H_DIM + c;
    H4 sr; sr.u = *reinterpret_cast<const uint4*>(zsH + idx);
    float s[8];
    {
        float2 f0 = __half22float2(sr.h[0]), f1 = __half22float2(sr.h[1]);
        float2 f2 = __half22float2(sr.h[2]), f3 = __half22float2(sr.h[3]);
        s[0] = f0.x; s[1] = f0.y; s[2] = f1.x; s[3] = f1.y;
        s[4] = f2.x; s[5] = f2.y; s[6] = f3.x; s[7] = f3.y;
    }
    H4 xr; xr.u = *reinterpret_cast<const uint4*>(x0H + idx);
    float xv[8];
    {
        float2 f0 = __half22float2(xr.h[0]), f1 = __half22float2(xr.h[1]);
        float2 f2 = __half22float2(xr.h[2]), f3 = __half22float2(xr.h[3]);
        xv[0] = f0.x; xv[1] = f0.y; xv[2] = f1.x; xv[3] = f1.y;
        xv[4] = f2.x; xv[5] = f2.y; xv[6] = f3.x; xv[7] = f3.y;
    }
    float a = 0.5f / (1.f + __expf(-alpha[node]));

    float k[8];
    #pragma unroll
    for (int i = 0; i < 8; ++i) k[i] = fmaf(a, az[i] - s[i], xv[i]);

    float o[8];
    if constexpr (STAGE == 0) {
        H4 aw;
        aw.h[0] = __float22half2_rn(make_float2(k[0], k[1]));
        aw.h[1] = __float22half2_rn(make_float2(k[2], k[3]));
        aw.h[2] = __float22half2_rn(make_float2(k[4], k[5]));
        aw.h[3] = __float22half2_rn(make_float2(k[6], k[7]));
        *reinterpret_cast<uint4*>(accH + idx) = aw.u;
        #pragma unroll
        for (int i = 0; i < 8; ++i) o[i] = fmaf(cnext, k[i], s[i]);
    } else if constexpr (STAGE == 1 || STAGE == 2) {
        H4 ar; ar.u = *reinterpret_cast<const uint4*>(accH + idx);
        float av[8];
        {
            float2 f0 = __half22float2(ar.h[0]), f1 = __half22float2(ar.h[1]);
            float2 f2 = __half22float2(ar.h[2]), f3 = __half22float2(ar.h[3]);
            av[0] = f0.x; av[1] = f0.y; av[2] = f1.x; av[3] = f1.y;
            av[4] = f2.x; av[5] = f2.y; av[6] = f3.x; av[7] = f3.y;
        }
        #pragma unroll
        for (int i = 0; i < 8; ++i) av[i] = fmaf(2.f, k[i], av[i]);
        H4 aw;
        aw.h[0] = __float22half2_rn(make_float2(av[0], av[1]));
        aw.h[1] = __float22half2_rn(make_float2(av[2], av[3]));
        aw.h[2] = __float22half2_rn(make_float2(av[4], av[5]));
        aw.h[3] = __float22half2_rn(make_float2(av[6], av[7]));
        *reinterpret_cast<uint4*>(accH + idx) = aw.u;
        H4 br; br.u = *reinterpret_cast<const uint4*>(zH + idx);
        float bv[8];
        {
            float2 f0 = __half22float2(br.h[0]), f1 = __half22float2(br.h[1]);
            float2 f2 = __half22float2(br.h[2]), f3 = __half22float2(br.h[3]);
            bv[0] = f0.x; bv[1] = f0.y; bv[2] = f1.x; bv[3] = f1.y;
            bv[4] = f2.x; bv[5] = f2.y; bv[6] = f3.x; bv[7] = f3.y;
        }
        #pragma unroll
        for (int i = 0; i < 8; ++i) o[i] = fmaf(cnext, k[i], bv[i]);
    } else {
        H4 ar; ar.u = *reinterpret_cast<const uint4*>(accH + idx);
        float av[8];
        {
            float2 f0 = __half22float2(ar.h[0]), f1 = __half22float2(ar.h[1]);
            float2 f2 = __half22float2(ar.h[2]), f3 = __half22float2(ar.h[3]);
            av[0] = f0.x; av[1] = f0.y; av[2] = f1.x; av[3] = f1.y;
            av[4] = f2.x; av[5] = f2.y; av[6] = f3.x; av[7] = f3.y;
        }
        float4 zb0 = *reinterpret_cast<const float4*>(zbF + idx);
        float4 zb1 = *reinterpret_cast<const float4*>(zbF + idx + 4);
        float zb[8] = {zb0.x, zb0.y, zb0.z, zb0.w, zb1.x, zb1.y, zb1.z, zb1.w};
        #pragma unroll
        for (int i = 0; i < 8; ++i) o[i] = fmaf(cnext, av[i] + k[i], zb[i]);
        float4 oz0 = make_float4(o[0], o[1], o[2], o[3]);
        float4 oz1 = make_float4(o[4], o[5], o[6], o[7]);
        *reinterpret_cast<float4*>(outZ + idx)     = oz0;
        *reinterpret_cast<float4*>(outZ + idx + 4) = oz1;
    }
    H4 sv;
    sv.h[0] = __float22half2_rn(make_float2(o[0], o[1]));
    sv.h[1] = __float22half2_rn(make_float2(o[2], o[3]));
    sv.h[2] = __float22half2_rn(make_float2(o[4], o[5]));
    sv.h[3] = __float22half2_rn(make_float2(o[6], o[7]));
    *reinterpret_cast<uint4*>(outH + idx) = sv.u;
}

// ---------------- Decoder: out = relu(z) @ m2_w + m2_b ----------------
__global__ __launch_bounds__(256) void decoder_kernel(
    const float* __restrict__ z, const float* __restrict__ W2,
    const float* __restrict__ b2, float* __restrict__ out)
{
    __shared__ float zsm[4][H_DIM];
    int lane = threadIdx.x & 63;
    int w    = threadIdx.x >> 6;
    int node = blockIdx.x * 4 + w;
    int ld   = node >= N_NODES ? N_NODES - 1 : node;
    float zv = z[(size_t)ld * H_DIM + lane];
    zsm[w][lane] = zv > 0.f ? zv : 0.f;
    __syncthreads();
    if (node < N_NODES && lane < C_OUT) {
        float acc = b2[lane];
        #pragma unroll
        for (int k = 0; k < H_DIM; ++k)
            acc = fmaf(zsm[w][k], W2[k * C_OUT + lane], acc);
        out[(size_t)node * C_OUT + lane] = acc;
    }
}

extern "C" void kernel_launch(void* const* d_in, const int* in_sizes, int n_in,
                              void* d_out, int out_size, void* d_ws, size_t ws_size,
                              hipStream_t stream)
{
    const float* x     = (const float*)d_in[0];
    const float* ew    = (const float*)d_in[1];
    const float* m1w   = (const float*)d_in[2];
    const float* m1b   = (const float*)d_in[3];
    const float* alpha = (const float*)d_in[4];
    const float* m2w   = (const float*)d_in[5];
    const float* m2b   = (const float*)d_in[6];
    const int*   esrc  = (const int*)d_in[7];
    const int*   edst  = (const int*)d_in[8];
    float* out = (float*)d_out;

    char* ws = (char*)d_ws;
    size_t o = 0;
    auto alloc = [&](size_t bytes) -> void* {
        void* p = ws + o;
        o = (o + bytes + 255) & ~(size_t)255;
        return p;
    };
    float*  z      = (float*)alloc((size_t)N_NODES * H_DIM * 4);
    __half* x0H    = (__half*)alloc((size_t)N_NODES * H_DIM * 2);
    __half* zH     = (__half*)alloc((size_t)N_NODES * H_DIM * 2);
    __half* ztAH   = (__half*)alloc((size_t)N_NODES * H_DIM * 2);
    __half* ztBH   = (__half*)alloc((size_t)N_NODES * H_DIM * 2);
    __half* accH   = (__half*)alloc((size_t)N_NODES * H_DIM * 2);
    __half* bfrag  = (__half*)alloc((size_t)KTILES * 4 * 64 * 8 * 2);
    int*    counts = (int*)alloc((size_t)N_NODES * 4);
    int*    off    = (int*)alloc((size_t)(N_NODES + 1) * 4);
    int*    cursor = (int*)alloc((size_t)N_NODES * 4);
    int*    bsums  = (int*)alloc((size_t)NB_SCAN * 4);
    int*    bbases = (int*)alloc((size_t)NB_SCAN * 4);
    int2*   epack  = (int2*)alloc((size_t)N_EDGES * 8);

    hipMemsetAsync(counts, 0, (size_t)N_NODES * 4, stream);
    hist_kernel<<<(N_EDGES + 255) / 256, 256, 0, stream>>>(esrc, counts);
    scanA_kernel<<<NB_SCAN, 256, 0, stream>>>(counts, bsums);
    scanB_kernel<<<1, 256, 0, stream>>>(bsums, bbases);
    scanC_kernel<<<NB_SCAN, 256, 0, stream>>>(counts, bbases, off, cursor);
    scatter_kernel<<<(N_EDGES + 255) / 256, 256, 0, stream>>>(esrc, edst, ew, cursor, epack);

    bfrag_kernel<<<(KTILES * 4 * 64 + 255) / 256, 256, 0, stream>>>(m1w, bfrag);
    encoder_kernel<<<(N_NODES + 31) / 32, 256, 0, stream>>>(x, bfrag, m1b, x0H, z, zH);

    const float dt = 1.0f / STEPS;
    int sgrid = (N_NODES + 31) / 32;
    for (int step = 0; step < STEPS; ++step) {
        stage_kernel<0><<<sgrid, 256, 0, stream>>>(off, epack, zH,   zH, nullptr, x0H, alpha, accH, ztAH, nullptr, 0.5f * dt);
        stage_kernel<1><<<sgrid, 256, 0, stream>>>(off, epack, ztAH, zH, nullptr, x0H, alpha, accH, ztBH, nullptr, 0.5f * dt);
        stage_kernel<2><<<sgrid, 256, 0, stream>>>(off, epack, ztBH, zH, nullptr, x0H, alpha, accH, ztAH, nullptr, dt);
        stage_kernel<3><<<sgrid, 256, 0, stream>>>(off, epack, ztAH, zH, z,       x0H, alpha, accH, zH,   z,       dt / 6.0f);
    }

    decoder_kernel<<<(N_NODES + 3) / 4, 256, 0, stream>>>(z, m2w, m2b, out);
}